// Round 2
// baseline (117.087 us; speedup 1.0000x reference)
//
#include <hip/hip_runtime.h>
#include <hip/hip_bf16.h>
#include <stdint.h>

#define BB 4
#define NN 4096
#define DD 128

typedef __attribute__((ext_vector_type(8))) short short8;
typedef __attribute__((ext_vector_type(4))) float f32x4;

static __device__ __forceinline__ unsigned short f2bf(float f) {
  unsigned u = __builtin_bit_cast(unsigned, f);
  u += 0x7fffu + ((u >> 16) & 1u);   // round-to-nearest-even
  return (unsigned short)(u >> 16);
}
static __device__ __forceinline__ float bf2f(unsigned short s) {
  return __builtin_bit_cast(float, (unsigned)s << 16);
}

// ---------------- kernel 1: deg -> dinv ----------------
__global__ __launch_bounds__(256) void k_deg(const float* __restrict__ A,
                                             float* __restrict__ dinv) {
  const int row = blockIdx.x;                 // b*N + n
  const float* a = A + (size_t)row * NN;
  float s = 0.f;
  for (int i = threadIdx.x * 4; i < NN; i += 256 * 4) {
    const float4 v = *reinterpret_cast<const float4*>(a + i);
    s += (v.x + v.y) + (v.z + v.w);
  }
  for (int off = 32; off > 0; off >>= 1) s += __shfl_down(s, off, 64);
  __shared__ float red[4];
  if ((threadIdx.x & 63) == 0) red[threadIdx.x >> 6] = s;
  __syncthreads();
  if (threadIdx.x == 0) {
    const float deg = (red[0] + red[1]) + (red[2] + red[3]) + 1.0f;
    dinv[row] = 1.0f / sqrtf(deg);
  }
}

// ---------------- kernel 2: Y = d_m * X (bf16), transposed + row copies ----------------
__global__ __launch_bounds__(256) void k_prep(const float* __restrict__ X,
                                              const float* __restrict__ dinv,
                                              unsigned short* __restrict__ Yt,  // [B][D][N]
                                              unsigned short* __restrict__ Yr)  // [B][N][D]
{
  __shared__ unsigned short tile[64][130];
  const int b = blockIdx.x >> 6;
  const int m0 = (blockIdx.x & 63) << 6;
  const float* Xb = X + ((size_t)b * NN + m0) * DD;
  const float* dv = dinv + b * NN + m0;
  for (int idx = threadIdx.x; idx < 64 * 128; idx += 256) {
    const int mi = idx >> 7, d = idx & 127;
    const unsigned short u = f2bf(Xb[mi * DD + d] * dv[mi]);
    tile[mi][d] = u;
    Yr[((size_t)b * NN + m0 + mi) * DD + d] = u;
  }
  __syncthreads();
  for (int idx = threadIdx.x; idx < 128 * 64; idx += 256) {
    const int d = idx >> 6, j = idx & 63;
    Yt[((size_t)b * DD + d) * NN + m0 + j] = tile[j][d];
  }
}

// ---------------- kernel 3: W -> bf16 ----------------
__global__ __launch_bounds__(256) void k_w(const float* __restrict__ W,
                                           unsigned short* __restrict__ Wb) {
  int idx = blockIdx.x * 1024 + threadIdx.x;
  for (int k = 0; k < 4; ++k, idx += 256) Wb[idx] = f2bf(W[idx]);
}

// ---------------- kernel 4: H = d_n * (A @ Y + Y) ----------------
// tile: BM=64 rows(n) x BN=128 cols(d), BK=64 over m. 8 waves (2x4), 32x32 per wave.
__global__ __launch_bounds__(512) void k_main(const float* __restrict__ A,
                                              const unsigned short* __restrict__ Yt,
                                              const unsigned short* __restrict__ Yr,
                                              const float* __restrict__ dinv,
                                              unsigned short* __restrict__ Hb) {
  // layout: [0,16K) = A dbuf (2 x 8K, [64][64] bf16, 128B rows, swizzled)
  //         [16K,48K) = Y dbuf (2 x 16K, [128][64] bf16, 128B rows, swizzled)
  __shared__ char lds[49152];

  const int tid = threadIdx.x;
  const int l   = tid & 63;
  const int wid = tid >> 6;
  const int b   = blockIdx.x >> 6;
  const int n0  = (blockIdx.x & 63) << 6;
  const int wr  = wid >> 2;     // 0..1
  const int wc  = wid & 3;      // 0..3

  const float* Ab = A + (size_t)(b * NN + n0) * NN;
  const unsigned short* Ytb = Yt + (size_t)b * DD * NN;

  // A staging: 2 float4 quads / thread
  const int ar0 = tid >> 4;                    // 0..31
  const int ar1 = ar0 + 32;
  const int ac4 = (tid & 15) << 2;             // f32 col 0..60
  const int aw0 = ar0 * 128 + ((ac4 << 1) ^ ((ar0 & 7) << 4));
  const int aw1 = ar1 * 128 + ((ac4 << 1) ^ ((ar1 & 7) << 4));

  // Yt staging: 2 x 16B chunks / thread
  const int yr0 = tid >> 3;                    // 0..63
  const int yr1 = yr0 + 64;                    // 64..127
  const int yc  = (tid & 7) << 4;              // byte col 0..112
  const int yw0 = yr0 * 128 + (yc ^ ((yr0 & 7) << 4));
  const int yw1 = yr1 * 128 + (yc ^ ((yr1 & 7) << 4));

  float4 ra0, ra1;
  uint4  ry0, ry1;

  auto LOAD = [&](int t) {
    ra0 = *reinterpret_cast<const float4*>(Ab + (size_t)ar0 * NN + t * 64 + ac4);
    ra1 = *reinterpret_cast<const float4*>(Ab + (size_t)ar1 * NN + t * 64 + ac4);
    ry0 = *reinterpret_cast<const uint4*>(Ytb + (size_t)yr0 * NN + t * 64 + (yc >> 1));
    ry1 = *reinterpret_cast<const uint4*>(Ytb + (size_t)yr1 * NN + t * 64 + (yc >> 1));
  };
  auto WRITE = [&](int nb) {
    char* As = lds + nb * 8192;
    char* Ys = lds + 16384 + nb * 16384;
    *reinterpret_cast<ushort4*>(As + aw0) =
        make_ushort4(f2bf(ra0.x), f2bf(ra0.y), f2bf(ra0.z), f2bf(ra0.w));
    *reinterpret_cast<ushort4*>(As + aw1) =
        make_ushort4(f2bf(ra1.x), f2bf(ra1.y), f2bf(ra1.z), f2bf(ra1.w));
    *reinterpret_cast<uint4*>(Ys + yw0) = ry0;
    *reinterpret_cast<uint4*>(Ys + yw1) = ry1;
  };

  f32x4 acc[2][2] = {};
  const int lrow = l & 15;
  const int lk16 = (l >> 4) << 4;              // byte offset of 8-bf16 k-chunk

  const int arow0 = wr * 32 + lrow, arow1 = arow0 + 16;
  const int brow0 = wc * 32 + lrow, brow1 = brow0 + 16;
  const int abase0 = arow0 * 128, abase1 = arow1 * 128;
  const int bbase0 = brow0 * 128, bbase1 = brow1 * 128;
  const int amsk0 = (arow0 & 7) << 4, amsk1 = (arow1 & 7) << 4;
  const int bmsk0 = (brow0 & 7) << 4, bmsk1 = (brow1 & 7) << 4;

  LOAD(0);
  WRITE(0);
  __syncthreads();
  int cur = 0;
  const int NT = NN / 64;
  for (int t = 0; t < NT; ++t) {
    if (t + 1 < NT) LOAD(t + 1);               // issue-early
    const char* As_ = lds + cur * 8192;
    const char* Ys_ = lds + 16384 + cur * 16384;
#pragma unroll
    for (int ks = 0; ks < 2; ++ks) {
      const int kb = ks * 64 + lk16;
      const short8 a0 = *reinterpret_cast<const short8*>(As_ + abase0 + (kb ^ amsk0));
      const short8 a1 = *reinterpret_cast<const short8*>(As_ + abase1 + (kb ^ amsk1));
      const short8 b0 = *reinterpret_cast<const short8*>(Ys_ + bbase0 + (kb ^ bmsk0));
      const short8 b1 = *reinterpret_cast<const short8*>(Ys_ + bbase1 + (kb ^ bmsk1));
      acc[0][0] = __builtin_amdgcn_mfma_f32_16x16x32_bf16(a0, b0, acc[0][0], 0, 0, 0);
      acc[0][1] = __builtin_amdgcn_mfma_f32_16x16x32_bf16(a0, b1, acc[0][1], 0, 0, 0);
      acc[1][0] = __builtin_amdgcn_mfma_f32_16x16x32_bf16(a1, b0, acc[1][0], 0, 0, 0);
      acc[1][1] = __builtin_amdgcn_mfma_f32_16x16x32_bf16(a1, b1, acc[1][1], 0, 0, 0);
    }
    if (t + 1 < NT) WRITE(cur ^ 1);            // write-late (auto vmcnt)
    __syncthreads();
    cur ^= 1;
  }

  // epilogue: H = d_n * (acc + Y[n,d])
  const int rg = (l >> 4) << 2;
#pragma unroll
  for (int mi = 0; mi < 2; ++mi)
#pragma unroll
    for (int ni = 0; ni < 2; ++ni)
#pragma unroll
      for (int r = 0; r < 4; ++r) {
        const int n = n0 + wr * 32 + mi * 16 + rg + r;
        const int d = wc * 32 + ni * 16 + lrow;
        const size_t gi = (size_t)(b * NN + n) * DD + d;
        const float h = (acc[mi][ni][r] + bf2f(Yr[gi])) * dinv[b * NN + n];
        Hb[gi] = f2bf(h);
      }
}

// ---------------- kernel 5: out = H @ W^T + b ----------------
__global__ __launch_bounds__(512) void k_lin(const unsigned short* __restrict__ Hb,
                                             const unsigned short* __restrict__ Wb,
                                             const float* __restrict__ bias,
                                             float* __restrict__ out) {
  // layout: [0,16K) = H tile [64][128] bf16, 256B rows, swizzled
  //         [16K,48K) = W tile [128][128] bf16, 256B rows, swizzled
  __shared__ char lds[49152];

  const int tid = threadIdx.x;
  const int l   = tid & 63;
  const int wid = tid >> 6;
  const int wr  = wid >> 2;
  const int wc  = wid & 3;
  const size_t r0 = (size_t)blockIdx.x * 64;   // global row in [0, B*N)

#pragma unroll
  for (int i = 0; i < 2; ++i) {
    const int c = tid + i * 512;               // 0..1023
    const int row = c >> 4, colb = (c & 15) << 4;
    const uint4 v = *reinterpret_cast<const uint4*>(Hb + (r0 + row) * DD + (colb >> 1));
    *reinterpret_cast<uint4*>(lds + row * 256 + (colb ^ ((row & 7) << 4))) = v;
  }
#pragma unroll
  for (int i = 0; i < 4; ++i) {
    const int c = tid + i * 512;               // 0..2047
    const int row = c >> 4, colb = (c & 15) << 4;
    const uint4 v = *reinterpret_cast<const uint4*>(Wb + row * DD + (colb >> 1));
    *reinterpret_cast<uint4*>(lds + 16384 + row * 256 + (colb ^ ((row & 7) << 4))) = v;
  }
  __syncthreads();

  f32x4 acc[2][2] = {};
  const int lrow = l & 15;
  const int lk16 = (l >> 4) << 4;
  const int arow0 = wr * 32 + lrow, arow1 = arow0 + 16;
  const int brow0 = wc * 32 + lrow, brow1 = brow0 + 16;
#pragma unroll
  for (int ks = 0; ks < 4; ++ks) {
    const int kb = ks * 64 + lk16;
    const short8 a0 = *reinterpret_cast<const short8*>(lds + arow0 * 256 + (kb ^ ((arow0 & 7) << 4)));
    const short8 a1 = *reinterpret_cast<const short8*>(lds + arow1 * 256 + (kb ^ ((arow1 & 7) << 4)));
    const short8 b0 = *reinterpret_cast<const short8*>(lds + 16384 + brow0 * 256 + (kb ^ ((brow0 & 7) << 4)));
    const short8 b1 = *reinterpret_cast<const short8*>(lds + 16384 + brow1 * 256 + (kb ^ ((brow1 & 7) << 4)));
    acc[0][0] = __builtin_amdgcn_mfma_f32_16x16x32_bf16(a0, b0, acc[0][0], 0, 0, 0);
    acc[0][1] = __builtin_amdgcn_mfma_f32_16x16x32_bf16(a0, b1, acc[0][1], 0, 0, 0);
    acc[1][0] = __builtin_amdgcn_mfma_f32_16x16x32_bf16(a1, b0, acc[1][0], 0, 0, 0);
    acc[1][1] = __builtin_amdgcn_mfma_f32_16x16x32_bf16(a1, b1, acc[1][1], 0, 0, 0);
  }

  const int rg = (l >> 4) << 2;
#pragma unroll
  for (int mi = 0; mi < 2; ++mi)
#pragma unroll
    for (int ni = 0; ni < 2; ++ni) {
      const int o = wc * 32 + ni * 16 + lrow;
      const float bo = bias[o];
#pragma unroll
      for (int r = 0; r < 4; ++r) {
        const int nloc = wr * 32 + mi * 16 + rg + r;
        out[(r0 + nloc) * DD + o] = acc[mi][ni][r] + bo;
      }
    }
}

// ---------------- host ----------------
extern "C" void kernel_launch(void* const* d_in, const int* in_sizes, int n_in,
                              void* d_out, int out_size, void* d_ws, size_t ws_size,
                              hipStream_t stream) {
  const float* X    = (const float*)d_in[0];
  const float* A    = (const float*)d_in[1];
  const float* W    = (const float*)d_in[2];
  const float* bias = (const float*)d_in[3];
  float* out = (float*)d_out;

  char* ws = (char*)d_ws;
  float* dinv = (float*)ws;                                           // 64 KB
  unsigned short* Yt = (unsigned short*)(ws + 65536);                 // 4 MB
  unsigned short* Yr = Yt + (size_t)BB * DD * NN;                     // 4 MB
  unsigned short* Hb = Yr + (size_t)BB * NN * DD;                     // 4 MB
  unsigned short* Wb = Hb + (size_t)BB * NN * DD;                     // 32 KB

  k_deg <<<BB * NN, 256, 0, stream>>>(A, dinv);
  k_w   <<<16, 256, 0, stream>>>(W, Wb);
  k_prep<<<BB * (NN / 64), 256, 0, stream>>>(X, dinv, Yt, Yr);
  k_main<<<BB * (NN / 64), 512, 0, stream>>>(A, Yt, Yr, dinv, Hb);
  k_lin <<<(BB * NN) / 64, 512, 0, stream>>>(Hb, Wb, bias, out);
}